// Round 1
// baseline (96.311 us; speedup 1.0000x reference)
//
#include <hip/hip_runtime.h>

#define DM 2048
#define DS 16
#define BATCH 2
#define SEQ 4096
#define P (BATCH * DM)  // 4096 independent scans

// ws layout (floats):
//   [0,      S)   Abar  [DS][DM]   (exp(delta*A))
//   [S,     2S)   Bbar  [DS][DM]   (delta*B)
//   [2S,    3S)   PowL  [DS][DM]   (Abar^L)
//   [3S,    4S)   Ct    [DS][DM]   (C transposed)
//   [4S, ......)  Hloc  [NC][DS][P]
// S = DS*DM

__global__ __launch_bounds__(256) void k_params(const float* __restrict__ A_log,
                                                const float* __restrict__ B,
                                                const float* __restrict__ C,
                                                const float* __restrict__ delta,
                                                float* __restrict__ ws, int Lsteps) {
  int j = blockIdx.x * 256 + threadIdx.x;
  if (j >= DM * DS) return;
  int n = j / DM, d = j - n * DM;
  float dl = delta[d];
  float a = -expf(A_log[d * DS + n]);
  ws[j] = expf(dl * a);                              // Abar
  ws[DS * DM + j] = dl * B[d * DS + n];              // Bbar
  ws[2 * DS * DM + j] = expf(dl * a * (float)Lsteps);// Abar^L
  ws[3 * DS * DM + j] = C[d * DS + n];               // Ct
}

// Phase 1: per-chunk local scan from h=0; store h at chunk end.
__global__ __launch_bounds__(256) void k_local(const float* __restrict__ x,
                                               const float* __restrict__ ws,
                                               float* __restrict__ Hloc, int Lsteps) {
  int tid = blockIdx.x * 256 + threadIdx.x;
  int p = tid & (P - 1);
  int k = tid >> 12;            // P = 4096
  int b = p >> 11;              // DM = 2048
  int d = p & (DM - 1);
  const float* Abar = ws;
  const float* Bbar = ws + DS * DM;
  float ab[DS], bb[DS], h[DS];
#pragma unroll
  for (int n = 0; n < DS; n++) {
    ab[n] = Abar[n * DM + d];
    bb[n] = Bbar[n * DM + d];
    h[n] = 0.f;
  }
  const float* xp = x + ((size_t)b * SEQ + (size_t)k * Lsteps) * DM + d;
  for (int t = 0; t < Lsteps; t += 4) {
    float x0 = xp[0 * DM], x1 = xp[1 * DM], x2 = xp[2 * DM], x3 = xp[3 * DM];
#pragma unroll
    for (int n = 0; n < DS; n++) h[n] = fmaf(ab[n], h[n], bb[n] * x0);
#pragma unroll
    for (int n = 0; n < DS; n++) h[n] = fmaf(ab[n], h[n], bb[n] * x1);
#pragma unroll
    for (int n = 0; n < DS; n++) h[n] = fmaf(ab[n], h[n], bb[n] * x2);
#pragma unroll
    for (int n = 0; n < DS; n++) h[n] = fmaf(ab[n], h[n], bb[n] * x3);
    xp += 4 * DM;
  }
  float* Hp = Hloc + (size_t)(k * DS) * P + p;
#pragma unroll
  for (int n = 0; n < DS; n++) Hp[n * P] = h[n];
}

// Phase 2: serial prefix over chunks per (b,d); Hloc[k] becomes h at chunk-k START.
__global__ __launch_bounds__(256) void k_scan(float* __restrict__ Hloc,
                                              const float* __restrict__ ws, int nc) {
  int p = blockIdx.x * 256 + threadIdx.x;  // P threads
  int d = p & (DM - 1);
  const float* PowL = ws + 2 * DS * DM;
  float pw[DS], carry[DS];
#pragma unroll
  for (int n = 0; n < DS; n++) { pw[n] = PowL[n * DM + d]; carry[n] = 0.f; }
  for (int k = 0; k < nc; k++) {
    float* Hp = Hloc + (size_t)(k * DS) * P + p;
#pragma unroll
    for (int n = 0; n < DS; n++) {
      float tmp = Hp[n * P];
      Hp[n * P] = carry[n];
      carry[n] = fmaf(pw[n], carry[n], tmp);
    }
  }
}

// Phase 3: rescan each chunk from its true start state; emit y.
__global__ __launch_bounds__(256) void k_final(const float* __restrict__ x,
                                               const float* __restrict__ ws,
                                               const float* __restrict__ Hloc,
                                               const float* __restrict__ Dp,
                                               float* __restrict__ out, int Lsteps) {
  int tid = blockIdx.x * 256 + threadIdx.x;
  int p = tid & (P - 1);
  int k = tid >> 12;
  int b = p >> 11;
  int d = p & (DM - 1);
  const float* Abar = ws;
  const float* Bbar = ws + DS * DM;
  const float* Ct = ws + 3 * DS * DM;
  float ab[DS], bb[DS], cc[DS], h[DS];
#pragma unroll
  for (int n = 0; n < DS; n++) {
    ab[n] = Abar[n * DM + d];
    bb[n] = Bbar[n * DM + d];
    cc[n] = Ct[n * DM + d];
  }
  const float* Hp = Hloc + (size_t)(k * DS) * P + p;
#pragma unroll
  for (int n = 0; n < DS; n++) h[n] = Hp[n * P];
  float Dd = Dp[d];
  size_t off = ((size_t)b * SEQ + (size_t)k * Lsteps) * DM + d;
  const float* xp = x + off;
  float* yp = out + off;
  for (int t = 0; t < Lsteps; t += 4) {
    float x0 = xp[0 * DM], x1 = xp[1 * DM], x2 = xp[2 * DM], x3 = xp[3 * DM];
    float acc;
#define STEP(xv, idx)                                                              \
    {                                                                              \
      _Pragma("unroll") for (int n = 0; n < DS; n++)                               \
          h[n] = fmaf(ab[n], h[n], bb[n] * (xv));                                  \
      acc = Dd * (xv);                                                             \
      _Pragma("unroll") for (int n = 0; n < DS; n++) acc = fmaf(cc[n], h[n], acc); \
      yp[(idx) * DM] = acc;                                                        \
    }
    STEP(x0, 0)
    STEP(x1, 1)
    STEP(x2, 2)
    STEP(x3, 3)
#undef STEP
    xp += 4 * DM;
    yp += 4 * DM;
  }
}

extern "C" void kernel_launch(void* const* d_in, const int* in_sizes, int n_in,
                              void* d_out, int out_size, void* d_ws, size_t ws_size,
                              hipStream_t stream) {
  const float* x = (const float*)d_in[0];
  const float* A_log = (const float*)d_in[1];
  const float* B = (const float*)d_in[2];
  const float* C = (const float*)d_in[3];
  const float* Dp = (const float*)d_in[4];
  const float* delta = (const float*)d_in[5];
  float* out = (float*)d_out;
  float* ws = (float*)d_ws;

  // Pick chunk count that fits the workspace (Hloc = nc*DS*P floats).
  size_t base = 4 * (size_t)DS * DM;
  int nc = 64;
  while (nc > 1 && (base + (size_t)nc * DS * P) * 4 > ws_size) nc >>= 1;
  int Lsteps = SEQ / nc;
  float* Hloc = ws + base;

  k_params<<<(DM * DS + 255) / 256, 256, 0, stream>>>(A_log, B, C, delta, ws, Lsteps);
  k_local<<<(nc * P) / 256, 256, 0, stream>>>(x, ws, Hloc, Lsteps);
  k_scan<<<P / 256, 256, 0, stream>>>(Hloc, ws, nc);
  k_final<<<(nc * P) / 256, 256, 0, stream>>>(x, ws, Hloc, Dp, out, Lsteps);
}

// Round 2
// 59.659 us; speedup vs baseline: 1.6144x; 1.6144x over previous
//
#include <hip/hip_runtime.h>

#define DM 2048
#define DS 16
#define BATCH 2
#define SEQ 4096
#define P (BATCH * DM)  // 4096 independent scans

// ws layout (floats):
//   [0,      S)   Abar  [DS][DM]   (exp(delta*A))
//   [S,     2S)   Bbar  [DS][DM]   (delta*B)
//   [2S,    3S)   PowL  [DS][DM]   (Abar^L)
//   [3S,    4S)   Ct    [DS][DM]   (C transposed)
//   [4S, ......)  Hloc  [NC][DS][P]
// S = DS*DM

__global__ __launch_bounds__(256) void k_params(const float* __restrict__ A_log,
                                                const float* __restrict__ B,
                                                const float* __restrict__ C,
                                                const float* __restrict__ delta,
                                                float* __restrict__ ws, int Lsteps) {
  int j = blockIdx.x * 256 + threadIdx.x;
  if (j >= DM * DS) return;
  int n = j / DM, d = j - n * DM;
  float dl = delta[d];
  float a = -expf(A_log[d * DS + n]);
  ws[j] = expf(dl * a);                              // Abar
  ws[DS * DM + j] = dl * B[d * DS + n];              // Bbar
  ws[2 * DS * DM + j] = expf(dl * a * (float)Lsteps);// Abar^L
  ws[3 * DS * DM + j] = C[d * DS + n];               // Ct
}

// Phase 1: per-chunk local scan from h=0; store h at chunk end.
__global__ __launch_bounds__(256) void k_local(const float* __restrict__ x,
                                               const float* __restrict__ ws,
                                               float* __restrict__ Hloc, int Lsteps) {
  int tid = blockIdx.x * 256 + threadIdx.x;
  int p = tid & (P - 1);
  int k = tid >> 12;            // P = 4096
  int b = p >> 11;              // DM = 2048
  int d = p & (DM - 1);
  const float* Abar = ws;
  const float* Bbar = ws + DS * DM;
  float ab[DS], bb[DS], h[DS];
#pragma unroll
  for (int n = 0; n < DS; n++) {
    ab[n] = Abar[n * DM + d];
    bb[n] = Bbar[n * DM + d];
    h[n] = 0.f;
  }
  const float* xp = x + ((size_t)b * SEQ + (size_t)k * Lsteps) * DM + d;
  for (int t = 0; t < Lsteps; t += 4) {
    float x0 = xp[0 * DM], x1 = xp[1 * DM], x2 = xp[2 * DM], x3 = xp[3 * DM];
#pragma unroll
    for (int n = 0; n < DS; n++) h[n] = fmaf(ab[n], h[n], bb[n] * x0);
#pragma unroll
    for (int n = 0; n < DS; n++) h[n] = fmaf(ab[n], h[n], bb[n] * x1);
#pragma unroll
    for (int n = 0; n < DS; n++) h[n] = fmaf(ab[n], h[n], bb[n] * x2);
#pragma unroll
    for (int n = 0; n < DS; n++) h[n] = fmaf(ab[n], h[n], bb[n] * x3);
    xp += 4 * DM;
  }
  float* Hp = Hloc + (size_t)(k * DS) * P + p;
#pragma unroll
  for (int n = 0; n < DS; n++) Hp[n * P] = h[n];
}

// Phase 2: serial prefix over chunks, parallel over (n, p) = 65536 threads.
// Hloc[k][n][p] becomes the state at chunk-k START (exclusive scan with
// combine carry' = pw * carry + v).
__global__ __launch_bounds__(256) void k_scan(float* __restrict__ Hloc,
                                              const float* __restrict__ ws, int nc) {
  int tid = blockIdx.x * 256 + threadIdx.x;  // DS*P threads
  int p = tid & (P - 1);
  int n = tid >> 12;  // tid / P
  int d = p & (DM - 1);
  const float* PowL = ws + 2 * DS * DM;
  float pw = PowL[n * DM + d];
  float carry = 0.f;
  float* Hp = Hloc + (size_t)n * P + p;
  const size_t stride = (size_t)DS * P;
  // nc is 64 (or a smaller power of two); batch 16 loads for MLP.
  for (int k0 = 0; k0 < nc; k0 += 16) {
    float v[16];
#pragma unroll
    for (int j = 0; j < 16; j++) v[j] = Hp[(size_t)(k0 + j) * stride];
#pragma unroll
    for (int j = 0; j < 16; j++) {
      Hp[(size_t)(k0 + j) * stride] = carry;
      carry = fmaf(pw, carry, v[j]);
    }
  }
}

// Phase 3: rescan each chunk from its true start state; emit y.
__global__ __launch_bounds__(256) void k_final(const float* __restrict__ x,
                                               const float* __restrict__ ws,
                                               const float* __restrict__ Hloc,
                                               const float* __restrict__ Dp,
                                               float* __restrict__ out, int Lsteps) {
  int tid = blockIdx.x * 256 + threadIdx.x;
  int p = tid & (P - 1);
  int k = tid >> 12;
  int b = p >> 11;
  int d = p & (DM - 1);
  const float* Abar = ws;
  const float* Bbar = ws + DS * DM;
  const float* Ct = ws + 3 * DS * DM;
  float ab[DS], bb[DS], cc[DS], h[DS];
#pragma unroll
  for (int n = 0; n < DS; n++) {
    ab[n] = Abar[n * DM + d];
    bb[n] = Bbar[n * DM + d];
    cc[n] = Ct[n * DM + d];
  }
  const float* Hp = Hloc + (size_t)(k * DS) * P + p;
#pragma unroll
  for (int n = 0; n < DS; n++) h[n] = Hp[n * P];
  float Dd = Dp[d];
  size_t off = ((size_t)b * SEQ + (size_t)k * Lsteps) * DM + d;
  const float* xp = x + off;
  float* yp = out + off;
  for (int t = 0; t < Lsteps; t += 4) {
    float x0 = xp[0 * DM], x1 = xp[1 * DM], x2 = xp[2 * DM], x3 = xp[3 * DM];
    float acc;
#define STEP(xv, idx)                                                              \
    {                                                                              \
      _Pragma("unroll") for (int n = 0; n < DS; n++)                               \
          h[n] = fmaf(ab[n], h[n], bb[n] * (xv));                                  \
      acc = Dd * (xv);                                                             \
      _Pragma("unroll") for (int n = 0; n < DS; n++) acc = fmaf(cc[n], h[n], acc); \
      yp[(idx) * DM] = acc;                                                        \
    }
    STEP(x0, 0)
    STEP(x1, 1)
    STEP(x2, 2)
    STEP(x3, 3)
#undef STEP
    xp += 4 * DM;
    yp += 4 * DM;
  }
}

extern "C" void kernel_launch(void* const* d_in, const int* in_sizes, int n_in,
                              void* d_out, int out_size, void* d_ws, size_t ws_size,
                              hipStream_t stream) {
  const float* x = (const float*)d_in[0];
  const float* A_log = (const float*)d_in[1];
  const float* B = (const float*)d_in[2];
  const float* C = (const float*)d_in[3];
  const float* Dp = (const float*)d_in[4];
  const float* delta = (const float*)d_in[5];
  float* out = (float*)d_out;
  float* ws = (float*)d_ws;

  // Pick chunk count that fits the workspace (Hloc = nc*DS*P floats).
  size_t base = 4 * (size_t)DS * DM;
  int nc = 64;
  while (nc > 16 && (base + (size_t)nc * DS * P) * 4 > ws_size) nc >>= 1;
  int Lsteps = SEQ / nc;
  float* Hloc = ws + base;

  k_params<<<(DM * DS + 255) / 256, 256, 0, stream>>>(A_log, B, C, delta, ws, Lsteps);
  k_local<<<(nc * P) / 256, 256, 0, stream>>>(x, ws, Hloc, Lsteps);
  k_scan<<<(DS * P) / 256, 256, 0, stream>>>(Hloc, ws, nc);
  k_final<<<(nc * P) / 256, 256, 0, stream>>>(x, ws, Hloc, Dp, out, Lsteps);
}